// Round 11
// baseline (796.152 us; speedup 1.0000x reference)
//
#include <hip/hip_runtime.h>

typedef __attribute__((ext_vector_type(8))) short short8;
typedef __attribute__((ext_vector_type(4))) float floatx4;
typedef __attribute__((ext_vector_type(2))) unsigned int uintx2;
typedef __attribute__((ext_vector_type(4))) unsigned int uintx4;
typedef unsigned short u16;

#define MFMA(a, b, c) __builtin_amdgcn_mfma_f32_16x16x32_bf16((a), (b), (c), 0, 0, 0)

__device__ __forceinline__ u16 f2bf(float f) {
  unsigned int u = __builtin_bit_cast(unsigned int, f);
  u += ((u >> 16) & 1u) + 0x7fffu;
  return (u16)(u >> 16);
}

__device__ __forceinline__ float softplus_f(float v) {
  float a = __builtin_fabsf(v);
  float e = __expf(-a);
  float l = __logf(1.0f + e);
  return __builtin_fmaxf(v, 0.0f) + l;
}

__device__ __forceinline__ unsigned int pack_sp(float lo, float hi) {
  return (unsigned int)f2bf(softplus_f(lo)) | ((unsigned int)f2bf(softplus_f(hi)) << 16);
}

// out[n*K + k] = bf16(in[k*N + n]); in is K x N row-major fp32
__global__ void transpose_cvt(const float* __restrict__ in, u16* __restrict__ out, int K, int N) {
  __shared__ float tile[32][33];
  const int bn = blockIdx.x * 32, bk = blockIdx.y * 32;
  const int tx = threadIdx.x, ty = threadIdx.y;  // 32 x 8
#pragma unroll
  for (int i = 0; i < 32; i += 8)
    tile[ty + i][tx] = in[(size_t)(bk + ty + i) * N + bn + tx];
  __syncthreads();
#pragma unroll
  for (int i = 0; i < 32; i += 8)
    out[(size_t)(bn + ty + i) * K + bk + tx] = f2bf(tile[tx][ty + i]);
}

__device__ __forceinline__ void gld16(const void* g, void* l) {
  __builtin_amdgcn_global_load_lds((const __attribute__((address_space(1))) void*)g,
                                   (__attribute__((address_space(3))) void*)l, 16, 0, 0);
}

template <int LN>
__device__ __forceinline__ void vwait() {
  if constexpr (LN == 0) asm volatile("s_waitcnt vmcnt(0)" ::: "memory");
  else if constexpr (LN == 4) asm volatile("s_waitcnt vmcnt(4)" ::: "memory");
  else if constexpr (LN == 9) asm volatile("s_waitcnt vmcnt(9)" ::: "memory");
  else if constexpr (LN == 10) asm volatile("s_waitcnt vmcnt(10)" ::: "memory");
  else if constexpr (LN == 12) asm volatile("s_waitcnt vmcnt(12)" ::: "memory");
}

// ---- BM x 256 GEMM (C = act @ wt^T): W direct global->reg, act-only in LDS ----
// Act half-tile [BM][32k] bf16 = permuted 16B granules (perm h(r)=(r>>1)&3,
// granule (r,g) at slot r*4+(g^h(r))): conflict-free b128 frag reads, 64B-coalesced
// staging. 4 slots rotate; ONE barrier per phase:
//   { load W(p+1)->regs; stage act(p+2)->slot (p+2)&3; vmcnt(pre-counted);
//     barrier; read MT act frags slot p&3; MT*4 MFMA (W regs from last phase) }
// Race-free: slot staged at p holds act(p-2); all waves drained those reads
// (lgkm before their MFMA(p-2)) before passing barrier(p-1), which precedes any
// phase-p stage issue. Establishment: per-wave vmcnt retires own act(p)+W(p);
// barrier then makes all waves' stages visible.
template <int K, int EPI, int BM, bool ACTF32>
__global__ __launch_bounds__(512, 2) void gemmw(const void* __restrict__ actv,
                                                const u16* __restrict__ wt,
                                                void* __restrict__ Cout, int N, int nbn) {
  constexpr int JA = BM / 128;      // act stage ops/thread/phase
  constexpr int MT = BM / 32;       // m-frags per wave
  constexpr int SLOT = BM * 32;     // u16 per act half-tile
  constexpr int H = K / 32;
  constexpr int LSZ = BM * 256;     // u16: max(4*SLOT, epilogue)
  __shared__ u16 lds[LSZ];
  u16* L = lds;
  const int tid = threadIdx.x, lane = tid & 63, wv = tid >> 6;
  const int l15 = lane & 15, g = lane >> 4;
  const int wvm = wv >> 2, wvn = wv & 3;  // 2 x 4 wave grid; wave owns (BM/2)m x 64n
  const int nwg = gridDim.x, o = blockIdx.x;
  const int sw = (o & 7) * (nwg >> 3) + (o >> 3);  // XCD swizzle (nwg % 8 == 0)
  const int bm = sw / nbn, bn = sw % nbn;
  const size_t am0 = (size_t)bm * BM;
  const size_t wn0 = (size_t)bn * 256;

  // act fragment offsets (slot-relative, u16 units)
  int bfo[MT];
#pragma unroll
  for (int mt = 0; mt < MT; ++mt) {
    const int r = wvm * (BM / 2) + mt * 16 + l15;
    bfo[mt] = (r * 4 + (g ^ ((r >> 1) & 3))) * 8;
  }
  // W fragment pointers (per-lane, direct global)
  const u16* wp[4];
#pragma unroll
  for (int t = 0; t < 4; ++t)
    wp[t] = wt + (wn0 + wvn * 64 + t * 16 + l15) * (size_t)K + g * 8;
  // act stage addressing
  const int rt = tid >> 2, ggt = (tid & 3) ^ ((rt >> 1) & 3);
  const int dstt = tid * 8;
  const u16* asrc = nullptr;
  const float* fsrc = nullptr;
  if constexpr (ACTF32) fsrc = (const float*)actv + (am0 + rt) * K + ggt * 8;
  else asrc = (const u16*)actv + (am0 + rt) * K + ggt * 8;

  floatx4 acc[4][MT];
  const floatx4 z4 = {0.f, 0.f, 0.f, 0.f};
#pragma unroll
  for (int t = 0; t < 4; ++t)
#pragma unroll
    for (int mt = 0; mt < MT; ++mt) acc[t][mt] = z4;

  short8 wfA[4], wfB[4];

#define STG_BF16(hh)                                                              \
  _Pragma("unroll") for (int j = 0; j < JA; ++j)                                  \
      gld16(asrc + (size_t)j * 128 * K + (hh) * 32,                               \
            L + ((hh) & 3) * SLOT + j * 4096 + dstt);
#define STG_F32(hh)                                                               \
  {                                                                               \
    floatx4 av[JA][2];                                                            \
    _Pragma("unroll") for (int j = 0; j < JA; ++j) {                              \
      av[j][0] = *(const floatx4*)(fsrc + (size_t)j * 128 * K + (hh) * 32);       \
      av[j][1] = *(const floatx4*)(fsrc + (size_t)j * 128 * K + (hh) * 32 + 4);   \
    }                                                                             \
    _Pragma("unroll") for (int j = 0; j < JA; ++j) {                              \
      uintx4 w_;                                                                  \
      w_.x = (unsigned)f2bf(av[j][0].x) | ((unsigned)f2bf(av[j][0].y) << 16);     \
      w_.y = (unsigned)f2bf(av[j][0].z) | ((unsigned)f2bf(av[j][0].w) << 16);     \
      w_.z = (unsigned)f2bf(av[j][1].x) | ((unsigned)f2bf(av[j][1].y) << 16);     \
      w_.w = (unsigned)f2bf(av[j][1].z) | ((unsigned)f2bf(av[j][1].w) << 16);     \
      *(uintx4*)(L + ((hh) & 3) * SLOT + j * 4096 + dstt) = w_;                   \
    }                                                                             \
  }

  // prologue: stage act(0)->slot0, act(1)->slot1; load W(0)
  if constexpr (ACTF32) {
    STG_F32(0)
    STG_F32(1)
  } else {
    STG_BF16(0)
    STG_BF16(1)
  }
#pragma unroll
  for (int t = 0; t < 4; ++t) wfA[t] = *(const short8*)(wp[t]);

#define PHASE(p_, WC, WN)                                                         \
  {                                                                               \
    if ((p_) + 1 < H) {                                                           \
      _Pragma("unroll") for (int t = 0; t < 4; ++t)                               \
          WN[t] = *(const short8*)(wp[t] + ((p_) + 1) * 32);                      \
    }                                                                             \
    if constexpr (ACTF32) {                                                       \
      if ((p_) + 2 < H) STG_F32((p_) + 2)                                         \
      asm volatile("s_waitcnt lgkmcnt(0)" ::: "memory");                          \
    } else {                                                                      \
      if ((p_) + 2 < H) STG_BF16((p_) + 2)                                        \
      if ((p_) < H - 2) vwait<8 + 2 * JA>();                                      \
      else if ((p_) == H - 2) vwait<8 + JA>();                                    \
      else vwait<4>();                                                            \
    }                                                                             \
    __builtin_amdgcn_s_barrier();                                                 \
    asm volatile("" ::: "memory");                                                \
    short8 bf[MT];                                                                \
    const int sl_ = ((p_) & 3) * SLOT;                                            \
    _Pragma("unroll") for (int mt = 0; mt < MT; ++mt)                             \
        bf[mt] = *(const short8*)(L + sl_ + bfo[mt]);                             \
    __builtin_amdgcn_s_setprio(1);                                                \
    _Pragma("unroll") for (int mt = 0; mt < MT; ++mt)                             \
        _Pragma("unroll") for (int t = 0; t < 4; ++t)                             \
            acc[t][mt] = MFMA(WC[t], bf[mt], acc[t][mt]);                         \
    __builtin_amdgcn_s_setprio(0);                                                \
    asm volatile("" ::: "memory");                                                \
  }

#pragma unroll 1
  for (int it = 0; it < H / 2; ++it) {
    const int p0 = 2 * it, p1 = 2 * it + 1;
    PHASE(p0, wfA, wfB)
    PHASE(p1, wfB, wfA)
  }
#undef PHASE
#undef STG_BF16
#undef STG_F32

  __syncthreads();  // all waves done reading staging slots; LDS reusable

  if constexpr (EPI == 0) {
    // softplus -> bf16 C via LDS transpose, one pass (BM*256 u16)
    u16* cl = L;
#pragma unroll
    for (int t = 0; t < 4; ++t)
#pragma unroll
      for (int mt = 0; mt < MT; ++mt) {
        const int m = wvm * (BM / 2) + mt * 16 + l15;
        const int n0 = wvn * 64 + t * 16 + g * 4;
        const int j = n0 >> 3, hh = (n0 >> 2) & 1;
        uintx2 pk;
        pk.x = pack_sp(acc[t][mt].x, acc[t][mt].y);
        pk.y = pack_sp(acc[t][mt].z, acc[t][mt].w);
        *(uintx2*)(cl + m * 256 + ((j ^ (m & 7)) << 3) + (hh << 2)) = pk;
      }
    __syncthreads();
    u16* outp = (u16*)Cout;
#pragma unroll
    for (int i = 0; i < BM / 16; ++i) {
      const int c = i * 512 + tid;
      const int m = c >> 5, j = c & 31;
      uintx4 v = *(const uintx4*)(cl + m * 256 + ((j ^ (m & 7)) << 3));
      *(uintx4*)(outp + (am0 + m) * N + wn0 + j * 8) = v;
    }
  } else {
    // fp32 C in two (BM/2)-row passes
    float* cf = (float*)L;
    constexpr int R = BM / 2;
#pragma unroll
    for (int q = 0; q < 2; ++q) {
      if (q) __syncthreads();
      if (wvm == q) {
#pragma unroll
        for (int t = 0; t < 4; ++t)
#pragma unroll
          for (int mt = 0; mt < MT; ++mt) {
            const int m = mt * 16 + l15;
            const int p = (wvn * 64 + t * 16 + g * 4) >> 1;
            *(floatx4*)(cf + m * 256 + ((p ^ ((m & 7) << 1)) << 1)) = acc[t][mt];
          }
      }
      __syncthreads();
      float* outp = (float*)Cout;
#pragma unroll
      for (int i = 0; i < R / 8; ++i) {
        const int c = i * 512 + tid;
        const int m = c >> 6, cc = c & 63;
        const int p = cc * 2;
        floatx4 v = *(const floatx4*)(cf + m * 256 + ((p ^ ((m & 7) << 1)) << 1));
        *(floatx4*)(outp + (am0 + q * R + m) * N + wn0 + cc * 4) = v;
      }
    }
  }
}

// ---------------- fallback: R1 fused kernel (used only if ws is too small) ----------------
__global__ __launch_bounds__(512, 2) void mlp3_fused(const float* __restrict__ x,
                                                     const u16* __restrict__ w1t,
                                                     const u16* __restrict__ w2t,
                                                     const u16* __restrict__ w3t,
                                                     float* __restrict__ out) {
  __shared__ u16 h1s[64 * 1024];
  __shared__ u16 xs[64 * 256];
  const int tid = threadIdx.x, lane = tid & 63, wv = tid >> 6;
  const int l15 = lane & 15, g = lane >> 4;
  const size_t m0 = (size_t)blockIdx.x * 64;
  const floatx4 z4 = {0.f, 0.f, 0.f, 0.f};
  {
    const float* xp = x + m0 * 256;
#pragma unroll
    for (int r = 0; r < 8; ++r) {
      int idx4 = r * 512 + tid;
      int m = idx4 >> 6, k = (idx4 & 63) << 2;
      floatx4 v = *(const floatx4*)(xp + m * 256 + k);
      uintx2 pk;
      pk.x = (unsigned)f2bf(v.x) | ((unsigned)f2bf(v.y) << 16);
      pk.y = (unsigned)f2bf(v.z) | ((unsigned)f2bf(v.w) << 16);
      *(uintx2*)(xs + ((m * 256 + k) ^ ((m & 7) << 3))) = pk;
    }
  }
  __syncthreads();
#pragma unroll 1
  for (int c = 0; c < 4; ++c) {
    floatx4 acc[2][4];
#pragma unroll
    for (int t = 0; t < 2; ++t)
#pragma unroll
      for (int mt = 0; mt < 4; ++mt) acc[t][mt] = z4;
    const u16* p0 = w1t + (size_t)(c * 256 + wv * 32 + l15) * 256;
#pragma unroll
    for (int ks = 0; ks < 8; ++ks) {
      const int k = ks * 32 + g * 8;
      short8 a0 = *(const short8*)(p0 + k);
      short8 a1 = *(const short8*)(p0 + 16 * 256 + k);
      short8 b0 = *(const short8*)(xs + (((0 * 16 + l15) * 256 + k) ^ ((l15 & 7) << 3)));
      short8 b1 = *(const short8*)(xs + (((1 * 16 + l15) * 256 + k) ^ ((l15 & 7) << 3)));
      short8 b2 = *(const short8*)(xs + (((2 * 16 + l15) * 256 + k) ^ ((l15 & 7) << 3)));
      short8 b3 = *(const short8*)(xs + (((3 * 16 + l15) * 256 + k) ^ ((l15 & 7) << 3)));
      acc[0][0] = MFMA(a0, b0, acc[0][0]); acc[0][1] = MFMA(a0, b1, acc[0][1]);
      acc[0][2] = MFMA(a0, b2, acc[0][2]); acc[0][3] = MFMA(a0, b3, acc[0][3]);
      acc[1][0] = MFMA(a1, b0, acc[1][0]); acc[1][1] = MFMA(a1, b1, acc[1][1]);
      acc[1][2] = MFMA(a1, b2, acc[1][2]); acc[1][3] = MFMA(a1, b3, acc[1][3]);
    }
#pragma unroll
    for (int t = 0; t < 2; ++t)
#pragma unroll
      for (int mt = 0; mt < 4; ++mt) {
        const int n1 = c * 256 + wv * 32 + t * 16 + g * 4;
        const int m = mt * 16 + l15;
        uintx2 pk;
        pk.x = pack_sp(acc[t][mt].x, acc[t][mt].y);
        pk.y = pack_sp(acc[t][mt].z, acc[t][mt].w);
        *(uintx2*)(h1s + ((m * 1024 + n1) ^ ((m & 7) << 3))) = pk;
      }
  }
  __syncthreads();
  floatx4 acc3[2][4];
#pragma unroll
  for (int t = 0; t < 2; ++t)
#pragma unroll
    for (int mt = 0; mt < 4; ++mt) acc3[t][mt] = z4;
#pragma unroll 1
  for (int c2 = 0; c2 < 4; ++c2) {
    floatx4 acc2[2][4];
#pragma unroll
    for (int t = 0; t < 2; ++t)
#pragma unroll
      for (int mt = 0; mt < 4; ++mt) acc2[t][mt] = z4;
    {
      const u16* p0 = w2t + (size_t)(c2 * 256 + wv * 32 + l15) * 1024;
#pragma unroll 4
      for (int ks = 0; ks < 32; ++ks) {
        const int k = ks * 32 + g * 8;
        short8 a0 = *(const short8*)(p0 + k);
        short8 a1 = *(const short8*)(p0 + 16 * 1024 + k);
        short8 b0 = *(const short8*)(h1s + (((0 * 16 + l15) * 1024 + k) ^ ((l15 & 7) << 3)));
        short8 b1 = *(const short8*)(h1s + (((1 * 16 + l15) * 1024 + k) ^ ((l15 & 7) << 3)));
        short8 b2 = *(const short8*)(h1s + (((2 * 16 + l15) * 1024 + k) ^ ((l15 & 7) << 3)));
        short8 b3 = *(const short8*)(h1s + (((3 * 16 + l15) * 1024 + k) ^ ((l15 & 7) << 3)));
        acc2[0][0] = MFMA(a0, b0, acc2[0][0]); acc2[0][1] = MFMA(a0, b1, acc2[0][1]);
        acc2[0][2] = MFMA(a0, b2, acc2[0][2]); acc2[0][3] = MFMA(a0, b3, acc2[0][3]);
        acc2[1][0] = MFMA(a1, b0, acc2[1][0]); acc2[1][1] = MFMA(a1, b1, acc2[1][1]);
        acc2[1][2] = MFMA(a1, b2, acc2[1][2]); acc2[1][3] = MFMA(a1, b3, acc2[1][3]);
      }
    }
    __syncthreads();
#pragma unroll
    for (int t = 0; t < 2; ++t)
#pragma unroll
      for (int mt = 0; mt < 4; ++mt) {
        const int n2l = wv * 32 + t * 16 + g * 4;
        const int m = mt * 16 + l15;
        uintx2 pk;
        pk.x = pack_sp(acc2[t][mt].x, acc2[t][mt].y);
        pk.y = pack_sp(acc2[t][mt].z, acc2[t][mt].w);
        *(uintx2*)(xs + ((m * 256 + n2l) ^ ((m & 7) << 3))) = pk;
      }
    __syncthreads();
    {
      const u16* p0 = w3t + (size_t)(wv * 32 + l15) * 1024 + c2 * 256;
#pragma unroll
      for (int ks = 0; ks < 8; ++ks) {
        const int k = ks * 32 + g * 8;
        short8 a0 = *(const short8*)(p0 + k);
        short8 a1 = *(const short8*)(p0 + 16 * 1024 + k);
        short8 b0 = *(const short8*)(xs + (((0 * 16 + l15) * 256 + k) ^ ((l15 & 7) << 3)));
        short8 b1 = *(const short8*)(xs + (((1 * 16 + l15) * 256 + k) ^ ((l15 & 7) << 3)));
        short8 b2 = *(const short8*)(xs + (((2 * 16 + l15) * 256 + k) ^ ((l15 & 7) << 3)));
        short8 b3 = *(const short8*)(xs + (((3 * 16 + l15) * 256 + k) ^ ((l15 & 7) << 3)));
        acc3[0][0] = MFMA(a0, b0, acc3[0][0]); acc3[0][1] = MFMA(a0, b1, acc3[0][1]);
        acc3[0][2] = MFMA(a0, b2, acc3[0][2]); acc3[0][3] = MFMA(a0, b3, acc3[0][3]);
        acc3[1][0] = MFMA(a1, b0, acc3[1][0]); acc3[1][1] = MFMA(a1, b1, acc3[1][1]);
        acc3[1][2] = MFMA(a1, b2, acc3[1][2]); acc3[1][3] = MFMA(a1, b3, acc3[1][3]);
      }
    }
  }
#pragma unroll
  for (int t = 0; t < 2; ++t)
#pragma unroll
    for (int mt = 0; mt < 4; ++mt) {
      const int n3 = wv * 32 + t * 16 + g * 4;
      const int m = mt * 16 + l15;
      *(floatx4*)(out + (m0 + m) * 256 + n3) = acc3[t][mt];
    }
}

extern "C" void kernel_launch(void* const* d_in, const int* in_sizes, int n_in,
                              void* d_out, int out_size, void* d_ws, size_t ws_size,
                              hipStream_t stream) {
  const float* x = (const float*)d_in[0];
  const float* w1 = (const float*)d_in[1];
  const float* w2 = (const float*)d_in[2];
  const float* w3 = (const float*)d_in[3];
  float* out = (float*)d_out;
  const size_t M = 131072;

  u16* w1t = (u16*)d_ws;                      // [1024][256]
  u16* w2t = w1t + 1024 * 256;                // [1024][1024]
  u16* w3t = w2t + 1024 * 1024;               // [256][1024]
  u16* bufA = w3t + 256 * 1024;               // h1: CM x 1024 bf16
  const size_t weights_el = 1024 * 256 + 1024 * 1024 + 256 * 1024;

  size_t CM = 0;
  const size_t cands[4] = {32768, 16384, 8192, 4096};
  for (int i = 0; i < 4; ++i) {
    size_t need = (weights_el + 2 * cands[i] * 1024) * sizeof(u16);
    if (ws_size >= need) { CM = cands[i]; break; }
  }

  dim3 tb(32, 8);
  transpose_cvt<<<dim3(32, 8), tb, 0, stream>>>(w1, w1t, 256, 1024);
  transpose_cvt<<<dim3(32, 32), tb, 0, stream>>>(w2, w2t, 1024, 1024);
  transpose_cvt<<<dim3(8, 32), tb, 0, stream>>>(w3, w3t, 1024, 256);

  if (CM) {
    u16* bufB = bufA + CM * 1024;
    const int nchunk = (int)(M / CM);
    for (int ci = 0; ci < nchunk; ++ci) {
      const float* xc = x + (size_t)ci * CM * 256;
      float* oc = out + (size_t)ci * CM * 256;
      gemmw<256, 0, 256, true><<<(int)(CM / 256) * 4, 512, 0, stream>>>(xc, w1t, bufA, 1024, 4);
      gemmw<1024, 0, 256, false><<<(int)(CM / 256) * 4, 512, 0, stream>>>(bufA, w2t, bufB, 1024, 4);
      gemmw<1024, 1, 128, false><<<(int)(CM / 128), 512, 0, stream>>>(bufB, w3t, oc, 256, 1);
    }
  } else {
    mlp3_fused<<<M / 64, 512, 0, stream>>>(x, w1t, w2t, w3t, out);
  }
}

// Round 12
// 708.682 us; speedup vs baseline: 1.1234x; 1.1234x over previous
//
#include <hip/hip_runtime.h>

typedef __attribute__((ext_vector_type(8))) short short8;
typedef __attribute__((ext_vector_type(4))) float floatx4;
typedef __attribute__((ext_vector_type(2))) unsigned int uintx2;
typedef __attribute__((ext_vector_type(4))) unsigned int uintx4;
typedef unsigned short u16;

#define MFMA(a, b, c) __builtin_amdgcn_mfma_f32_16x16x32_bf16((a), (b), (c), 0, 0, 0)
#define BAR() do { asm volatile("" ::: "memory"); __builtin_amdgcn_s_barrier(); \
                   asm volatile("" ::: "memory"); } while (0)
#define LGKM0() asm volatile("s_waitcnt lgkmcnt(0)" ::: "memory")

__device__ __forceinline__ u16 f2bf(float f) {
  unsigned int u = __builtin_bit_cast(unsigned int, f);
  u += ((u >> 16) & 1u) + 0x7fffu;
  return (u16)(u >> 16);
}

__device__ __forceinline__ float softplus_f(float v) {
  float a = __builtin_fabsf(v);
  float e = __expf(-a);
  float l = __logf(1.0f + e);
  return __builtin_fmaxf(v, 0.0f) + l;
}

__device__ __forceinline__ unsigned int pack_sp(float lo, float hi) {
  return (unsigned int)f2bf(softplus_f(lo)) | ((unsigned int)f2bf(softplus_f(hi)) << 16);
}

// out[n*K + k] = bf16(in[k*N + n]); in is K x N row-major fp32
__global__ void transpose_cvt(const float* __restrict__ in, u16* __restrict__ out, int K, int N) {
  __shared__ float tile[32][33];
  const int bn = blockIdx.x * 32, bk = blockIdx.y * 32;
  const int tx = threadIdx.x, ty = threadIdx.y;  // 32 x 8
#pragma unroll
  for (int i = 0; i < 32; i += 8)
    tile[ty + i][tx] = in[(size_t)(bk + ty + i) * N + bn + tx];
  __syncthreads();
#pragma unroll
  for (int i = 0; i < 32; i += 8)
    out[(size_t)(bn + ty + i) * K + bk + tx] = f2bf(tile[tx][ty + i]);
}

__device__ __forceinline__ void gld16(const void* g, void* l) {
  __builtin_amdgcn_global_load_lds((const __attribute__((address_space(1))) void*)g,
                                   (__attribute__((address_space(3))) void*)l, 16, 0, 0);
}

// ======== 256x256 GEMM (C = act @ wt^T), m201-style 8-phase/2-tile schedule ========
// K-tile BK=64; 4 half-tiles/tile (A-lo,A-hi,W-lo,W-hi; 128 rows x 64 k = 16 KB),
// 2 buffers = 128 KB. Half layout: slot(r,gg) = r*8 + (gg ^ ((r>>1)&7)); b128 frag
// reads 2-way-free; stage = 2 gld16/thread (slot s = j*512+tid), row-contiguous.
// Per tile, 4 phases; each: {ds_reads + 1 half-tile stage -> [vmcnt(4) @P3] -> BAR
// -> lgkmcnt(0) -> setprio -> 16 MFMA (one C-quadrant) -> setprio -> BAR}.
// Stage slots: P0:W-lo(t+1), P1:W-hi(t+1), P2:A-lo(t+2), P3:A-hi(t+2) — each slot's
// last read is >=1 end-barrier before its restage. vmcnt(4)@P3 retires exactly
// A(t+1)+W(t+1); 4 loads stay in flight across the barrier. k32 offset = k0 ^ 32.
template <int K, int EPI, bool ACTF32>
__global__ __launch_bounds__(512, 2) void gemm8(const void* __restrict__ actv,
                                                const u16* __restrict__ wt,
                                                void* __restrict__ Cout, int N, int nbn) {
  constexpr int H = K / 64;  // K-tiles
  __shared__ u16 lds[2 * 4 * 8192];  // [buf][half: Alo,Ahi,Wlo,Whi][8192 u16] = 128 KB
  u16* L = lds;
  const int tid = threadIdx.x, lane = tid & 63, wv = tid >> 6;
  const int l15 = lane & 15, g = lane >> 4;
  const int wvm = wv >> 2, wvn = wv & 3;  // 2 x 4; wave owns 128m x 64n
  const int nwg = gridDim.x, o = blockIdx.x;
  const int sw = (o & 7) * (nwg >> 3) + (o >> 3);  // XCD swizzle (nwg % 8 == 0)
  const int bm = sw / nbn, bn = sw % nbn;
  const size_t am0 = (size_t)bm * 256;
  const size_t wn0 = (size_t)bn * 256;

  // fragment offsets (u16 units, within a half, k-chunk 0)
  int afo[8], wfo[4];
#pragma unroll
  for (int mt = 0; mt < 8; ++mt) {
    const int r = mt * 16 + l15;
    afo[mt] = (r * 8 + (g ^ ((r >> 1) & 7))) * 8;
  }
#pragma unroll
  for (int nt = 0; nt < 4; ++nt) {
    const int r = (wvn & 1) * 64 + nt * 16 + l15;
    wfo[nt] = (r * 8 + (g ^ ((r >> 1) & 7))) * 8;
  }
  const int aHalf = wvm * 8192;              // wave's A half (within buf)
  const int wHalf = (2 + (wvn >> 1)) * 8192; // wave's W half

  // staging addressing: thread fills slots s = j*512 + tid (j = 0,1)
  int soff[2], sdst[2];
#pragma unroll
  for (int j = 0; j < 2; ++j) {
    const int s = j * 512 + tid;
    const int r = s >> 3, gg = (s & 7) ^ ((r >> 1) & 7);
    soff[j] = r * K + gg * 8;  // element offset within a half's 128-row band
    sdst[j] = s * 8;           // u16 offset within half
  }
  const u16* actb = nullptr;
  const float* factb = nullptr;
  if constexpr (ACTF32) factb = (const float*)actv + am0 * K;
  else actb = (const u16*)actv + am0 * K;
  const u16* wtb = wt + wn0 * K;

#define STG_W(tt, hi)                                                                \
  { _Pragma("unroll") for (int j = 0; j < 2; ++j)                                    \
      gld16(wtb + (size_t)(hi)*128 * K + soff[j] + (tt)*64,                          \
            L + ((tt)&1) * 32768 + (2 + (hi)) * 8192 + sdst[j]); }
#define STG_AB(tt, hi)                                                               \
  { _Pragma("unroll") for (int j = 0; j < 2; ++j)                                    \
      gld16(actb + (size_t)(hi)*128 * K + soff[j] + (tt)*64,                         \
            L + ((tt)&1) * 32768 + (hi)*8192 + sdst[j]); }
#define STG_AF(tt, hi)                                                               \
  { floatx4 v0[2], v1[2];                                                            \
    _Pragma("unroll") for (int j = 0; j < 2; ++j) {                                  \
      const float* sp_ = factb + (size_t)(hi)*128 * K + soff[j] + (tt)*64;           \
      v0[j] = *(const floatx4*)sp_;                                                  \
      v1[j] = *(const floatx4*)(sp_ + 4);                                            \
    }                                                                                \
    _Pragma("unroll") for (int j = 0; j < 2; ++j) {                                  \
      uintx4 w_;                                                                     \
      w_.x = (unsigned)f2bf(v0[j].x) | ((unsigned)f2bf(v0[j].y) << 16);              \
      w_.y = (unsigned)f2bf(v0[j].z) | ((unsigned)f2bf(v0[j].w) << 16);              \
      w_.z = (unsigned)f2bf(v1[j].x) | ((unsigned)f2bf(v1[j].y) << 16);              \
      w_.w = (unsigned)f2bf(v1[j].z) | ((unsigned)f2bf(v1[j].w) << 16);              \
      *(uintx4*)(L + ((tt)&1) * 32768 + (hi)*8192 + sdst[j]) = w_;                   \
    } }
#define STG_A(tt, hi)                                                                \
  { if constexpr (ACTF32) STG_AF(tt, hi) else STG_AB(tt, hi) }

  floatx4 acc[4][8];
  const floatx4 z4 = {0.f, 0.f, 0.f, 0.f};
#pragma unroll
  for (int t = 0; t < 4; ++t)
#pragma unroll
    for (int mt = 0; mt < 8; ++mt) acc[t][mt] = z4;

  // ---- prologue: tile0 all 4 halves + tile1 A halves; vmcnt(4) -> tile0 resident
  STG_W(0, 0) STG_W(0, 1) STG_A(0, 0) STG_A(0, 1)
  STG_A(1, 0) STG_A(1, 1)
  if constexpr (ACTF32) { asm volatile("s_waitcnt vmcnt(0)" ::: "memory"); LGKM0(); }
  else asm volatile("s_waitcnt vmcnt(4)" ::: "memory");
  BAR();

  short8 A0[8], A1[8], wf0, wf1;

#pragma unroll 1
  for (int t = 0; t < H; ++t) {
    const int cb = (t & 1) * 32768;
    // ---- P0: A@k0 (8) + W n01@k0 (2); stage W-lo(t+1); MFMA quad (n01, k0)
#pragma unroll
    for (int mt = 0; mt < 8; ++mt) A0[mt] = *(const short8*)(L + cb + aHalf + afo[mt]);
    wf0 = *(const short8*)(L + cb + wHalf + wfo[0]);
    wf1 = *(const short8*)(L + cb + wHalf + wfo[1]);
    if (t + 1 < H) STG_W(t + 1, 0)
    BAR(); LGKM0();
    __builtin_amdgcn_s_setprio(1);
#pragma unroll
    for (int mt = 0; mt < 8; ++mt) {
      acc[0][mt] = MFMA(wf0, A0[mt], acc[0][mt]);
      acc[1][mt] = MFMA(wf1, A0[mt], acc[1][mt]);
    }
    __builtin_amdgcn_s_setprio(0);
    BAR();
    // ---- P1: A@k32 (8) + W n01@k32 (2); stage W-hi(t+1); MFMA (n01, k32)
#pragma unroll
    for (int mt = 0; mt < 8; ++mt) A1[mt] = *(const short8*)(L + cb + aHalf + (afo[mt] ^ 32));
    wf0 = *(const short8*)(L + cb + wHalf + (wfo[0] ^ 32));
    wf1 = *(const short8*)(L + cb + wHalf + (wfo[1] ^ 32));
    if (t + 1 < H) STG_W(t + 1, 1)
    BAR(); LGKM0();
    __builtin_amdgcn_s_setprio(1);
#pragma unroll
    for (int mt = 0; mt < 8; ++mt) {
      acc[0][mt] = MFMA(wf0, A1[mt], acc[0][mt]);
      acc[1][mt] = MFMA(wf1, A1[mt], acc[1][mt]);
    }
    __builtin_amdgcn_s_setprio(0);
    BAR();
    // ---- P2: W n23@k0 (2); stage A-lo(t+2); MFMA (n23, k0) reusing A0
    wf0 = *(const short8*)(L + cb + wHalf + wfo[2]);
    wf1 = *(const short8*)(L + cb + wHalf + wfo[3]);
    if (t + 2 < H) STG_A(t + 2, 0)
    BAR(); LGKM0();
    __builtin_amdgcn_s_setprio(1);
#pragma unroll
    for (int mt = 0; mt < 8; ++mt) {
      acc[2][mt] = MFMA(wf0, A0[mt], acc[2][mt]);
      acc[3][mt] = MFMA(wf1, A0[mt], acc[3][mt]);
    }
    __builtin_amdgcn_s_setprio(0);
    BAR();
    // ---- P3: W n23@k32 (2); stage A-hi(t+2); vmcnt; MFMA (n23, k32) reusing A1
    wf0 = *(const short8*)(L + cb + wHalf + (wfo[2] ^ 32));
    wf1 = *(const short8*)(L + cb + wHalf + (wfo[3] ^ 32));
    if (t + 2 < H) STG_A(t + 2, 1)
    if (t < H - 2) asm volatile("s_waitcnt vmcnt(4)" ::: "memory");
    else if (t == H - 2) asm volatile("s_waitcnt vmcnt(0)" ::: "memory");
    BAR(); LGKM0();
    __builtin_amdgcn_s_setprio(1);
#pragma unroll
    for (int mt = 0; mt < 8; ++mt) {
      acc[2][mt] = MFMA(wf0, A1[mt], acc[2][mt]);
      acc[3][mt] = MFMA(wf1, A1[mt], acc[3][mt]);
    }
    __builtin_amdgcn_s_setprio(0);
    BAR();
  }
#undef STG_W
#undef STG_AB
#undef STG_AF
#undef STG_A

  __syncthreads();  // loop fully drained; LDS reusable for epilogue

  if constexpr (EPI == 0) {
    // softplus -> bf16 C via LDS transpose, one pass (256x256 = 128 KB)
    u16* cl = L;
#pragma unroll
    for (int t = 0; t < 4; ++t)
#pragma unroll
      for (int mt = 0; mt < 8; ++mt) {
        const int m = wvm * 128 + mt * 16 + l15;
        const int n0 = wvn * 64 + t * 16 + g * 4;
        const int j = n0 >> 3, hh = (n0 >> 2) & 1;
        uintx2 pk;
        pk.x = pack_sp(acc[t][mt].x, acc[t][mt].y);
        pk.y = pack_sp(acc[t][mt].z, acc[t][mt].w);
        *(uintx2*)(cl + m * 256 + ((j ^ (m & 7)) << 3) + (hh << 2)) = pk;
      }
    __syncthreads();
    u16* outp = (u16*)Cout;
#pragma unroll
    for (int i = 0; i < 16; ++i) {
      const int c = i * 512 + tid;
      const int m = c >> 5, j = c & 31;
      uintx4 v = *(const uintx4*)(cl + m * 256 + ((j ^ (m & 7)) << 3));
      *(uintx4*)(outp + (am0 + m) * N + wn0 + j * 8) = v;
    }
  } else {
    // fp32 C in two 128-row passes
    float* cf = (float*)L;
#pragma unroll
    for (int q = 0; q < 2; ++q) {
      if (q) __syncthreads();
      if (wvm == q) {
#pragma unroll
        for (int t = 0; t < 4; ++t)
#pragma unroll
          for (int mt = 0; mt < 8; ++mt) {
            const int m = mt * 16 + l15;
            const int p = (wvn * 64 + t * 16 + g * 4) >> 1;
            *(floatx4*)(cf + m * 256 + ((p ^ ((m & 7) << 1)) << 1)) = acc[t][mt];
          }
      }
      __syncthreads();
      float* outp = (float*)Cout;
#pragma unroll
      for (int i = 0; i < 16; ++i) {
        const int c = i * 512 + tid;
        const int m = c >> 6, cc = c & 63;
        const int p = cc * 2;
        floatx4 v = *(const floatx4*)(cf + m * 256 + ((p ^ ((m & 7) << 1)) << 1));
        *(floatx4*)(outp + (am0 + q * 128 + m) * N + wn0 + cc * 4) = v;
      }
    }
  }
}

// ---------------- fallback: R1 fused kernel (used only if ws is too small) ----------------
__global__ __launch_bounds__(512, 2) void mlp3_fused(const float* __restrict__ x,
                                                     const u16* __restrict__ w1t,
                                                     const u16* __restrict__ w2t,
                                                     const u16* __restrict__ w3t,
                                                     float* __restrict__ out) {
  __shared__ u16 h1s[64 * 1024];
  __shared__ u16 xs[64 * 256];
  const int tid = threadIdx.x, lane = tid & 63, wv = tid >> 6;
  const int l15 = lane & 15, g = lane >> 4;
  const size_t m0 = (size_t)blockIdx.x * 64;
  const floatx4 z4 = {0.f, 0.f, 0.f, 0.f};
  {
    const float* xp = x + m0 * 256;
#pragma unroll
    for (int r = 0; r < 8; ++r) {
      int idx4 = r * 512 + tid;
      int m = idx4 >> 6, k = (idx4 & 63) << 2;
      floatx4 v = *(const floatx4*)(xp + m * 256 + k);
      uintx2 pk;
      pk.x = (unsigned)f2bf(v.x) | ((unsigned)f2bf(v.y) << 16);
      pk.y = (unsigned)f2bf(v.z) | ((unsigned)f2bf(v.w) << 16);
      *(uintx2*)(xs + ((m * 256 + k) ^ ((m & 7) << 3))) = pk;
    }
  }
  __syncthreads();
#pragma unroll 1
  for (int c = 0; c < 4; ++c) {
    floatx4 acc[2][4];
#pragma unroll
    for (int t = 0; t < 2; ++t)
#pragma unroll
      for (int mt = 0; mt < 4; ++mt) acc[t][mt] = z4;
    const u16* p0 = w1t + (size_t)(c * 256 + wv * 32 + l15) * 256;
#pragma unroll
    for (int ks = 0; ks < 8; ++ks) {
      const int k = ks * 32 + g * 8;
      short8 a0 = *(const short8*)(p0 + k);
      short8 a1 = *(const short8*)(p0 + 16 * 256 + k);
      short8 b0 = *(const short8*)(xs + (((0 * 16 + l15) * 256 + k) ^ ((l15 & 7) << 3)));
      short8 b1 = *(const short8*)(xs + (((1 * 16 + l15) * 256 + k) ^ ((l15 & 7) << 3)));
      short8 b2 = *(const short8*)(xs + (((2 * 16 + l15) * 256 + k) ^ ((l15 & 7) << 3)));
      short8 b3 = *(const short8*)(xs + (((3 * 16 + l15) * 256 + k) ^ ((l15 & 7) << 3)));
      acc[0][0] = MFMA(a0, b0, acc[0][0]); acc[0][1] = MFMA(a0, b1, acc[0][1]);
      acc[0][2] = MFMA(a0, b2, acc[0][2]); acc[0][3] = MFMA(a0, b3, acc[0][3]);
      acc[1][0] = MFMA(a1, b0, acc[1][0]); acc[1][1] = MFMA(a1, b1, acc[1][1]);
      acc[1][2] = MFMA(a1, b2, acc[1][2]); acc[1][3] = MFMA(a1, b3, acc[1][3]);
    }
#pragma unroll
    for (int t = 0; t < 2; ++t)
#pragma unroll
      for (int mt = 0; mt < 4; ++mt) {
        const int n1 = c * 256 + wv * 32 + t * 16 + g * 4;
        const int m = mt * 16 + l15;
        uintx2 pk;
        pk.x = pack_sp(acc[t][mt].x, acc[t][mt].y);
        pk.y = pack_sp(acc[t][mt].z, acc[t][mt].w);
        *(uintx2*)(h1s + ((m * 1024 + n1) ^ ((m & 7) << 3))) = pk;
      }
  }
  __syncthreads();
  floatx4 acc3[2][4];
#pragma unroll
  for (int t = 0; t < 2; ++t)
#pragma unroll
    for (int mt = 0; mt < 4; ++mt) acc3[t][mt] = z4;
#pragma unroll 1
  for (int c2 = 0; c2 < 4; ++c2) {
    floatx4 acc2[2][4];
#pragma unroll
    for (int t = 0; t < 2; ++t)
#pragma unroll
      for (int mt = 0; mt < 4; ++mt) acc2[t][mt] = z4;
    {
      const u16* p0 = w2t + (size_t)(c2 * 256 + wv * 32 + l15) * 1024;
#pragma unroll 4
      for (int ks = 0; ks < 32; ++ks) {
        const int k = ks * 32 + g * 8;
        short8 a0 = *(const short8*)(p0 + k);
        short8 a1 = *(const short8*)(p0 + 16 * 1024 + k);
        short8 b0 = *(const short8*)(h1s + (((0 * 16 + l15) * 1024 + k) ^ ((l15 & 7) << 3)));
        short8 b1 = *(const short8*)(h1s + (((1 * 16 + l15) * 1024 + k) ^ ((l15 & 7) << 3)));
        short8 b2 = *(const short8*)(h1s + (((2 * 16 + l15) * 1024 + k) ^ ((l15 & 7) << 3)));
        short8 b3 = *(const short8*)(h1s + (((3 * 16 + l15) * 1024 + k) ^ ((l15 & 7) << 3)));
        acc2[0][0] = MFMA(a0, b0, acc2[0][0]); acc2[0][1] = MFMA(a0, b1, acc2[0][1]);
        acc2[0][2] = MFMA(a0, b2, acc2[0][2]); acc2[0][3] = MFMA(a0, b3, acc2[0][3]);
        acc2[1][0] = MFMA(a1, b0, acc2[1][0]); acc2[1][1] = MFMA(a1, b1, acc2[1][1]);
        acc2[1][2] = MFMA(a1, b2, acc2[1][2]); acc2[1][3] = MFMA(a1, b3, acc2[1][3]);
      }
    }
    __syncthreads();
#pragma unroll
    for (int t = 0; t < 2; ++t)
#pragma unroll
      for (int mt = 0; mt < 4; ++mt) {
        const int n2l = wv * 32 + t * 16 + g * 4;
        const int m = mt * 16 + l15;
        uintx2 pk;
        pk.x = pack_sp(acc2[t][mt].x, acc2[t][mt].y);
        pk.y = pack_sp(acc2[t][mt].z, acc2[t][mt].w);
        *(uintx2*)(xs + ((m * 256 + n2l) ^ ((m & 7) << 3))) = pk;
      }
    __syncthreads();
    {
      const u16* p0 = w3t + (size_t)(wv * 32 + l15) * 1024 + c2 * 256;
#pragma unroll
      for (int ks = 0; ks < 8; ++ks) {
        const int k = ks * 32 + g * 8;
        short8 a0 = *(const short8*)(p0 + k);
        short8 a1 = *(const short8*)(p0 + 16 * 1024 + k);
        short8 b0 = *(const short8*)(xs + (((0 * 16 + l15) * 256 + k) ^ ((l15 & 7) << 3)));
        short8 b1 = *(const short8*)(xs + (((1 * 16 + l15) * 256 + k) ^ ((l15 & 7) << 3)));
        short8 b2 = *(const short8*)(xs + (((2 * 16 + l15) * 256 + k) ^ ((l15 & 7) << 3)));
        short8 b3 = *(const short8*)(xs + (((3 * 16 + l15) * 256 + k) ^ ((l15 & 7) << 3)));
        acc3[0][0] = MFMA(a0, b0, acc3[0][0]); acc3[0][1] = MFMA(a0, b1, acc3[0][1]);
        acc3[0][2] = MFMA(a0, b2, acc3[0][2]); acc3[0][3] = MFMA(a0, b3, acc3[0][3]);
        acc3[1][0] = MFMA(a1, b0, acc3[1][0]); acc3[1][1] = MFMA(a1, b1, acc3[1][1]);
        acc3[1][2] = MFMA(a1, b2, acc3[1][2]); acc3[1][3] = MFMA(a1, b3, acc3[1][3]);
      }
    }
  }
#pragma unroll
  for (int t = 0; t < 2; ++t)
#pragma unroll
    for (int mt = 0; mt < 4; ++mt) {
      const int n3 = wv * 32 + t * 16 + g * 4;
      const int m = mt * 16 + l15;
      *(floatx4*)(out + (m0 + m) * 256 + n3) = acc3[t][mt];
    }
}

extern "C" void kernel_launch(void* const* d_in, const int* in_sizes, int n_in,
                              void* d_out, int out_size, void* d_ws, size_t ws_size,
                              hipStream_t stream) {
  const float* x = (const float*)d_in[0];
  const float* w1 = (const float*)d_in[1];
  const float* w2 = (const float*)d_in[2];
  const float* w3 = (const float*)d_in[3];
  float* out = (float*)d_out;
  const size_t M = 131072;

  u16* w1t = (u16*)d_ws;                      // [1024][256]
  u16* w2t = w1t + 1024 * 256;                // [1024][1024]
  u16* w3t = w2t + 1024 * 1024;               // [256][1024]
  u16* bufA = w3t + 256 * 1024;               // h1: CM x 1024 bf16
  const size_t weights_el = 1024 * 256 + 1024 * 1024 + 256 * 1024;

  size_t CM = 0;
  const size_t cands[4] = {32768, 16384, 8192, 4096};
  for (int i = 0; i < 4; ++i) {
    size_t need = (weights_el + 2 * cands[i] * 1024) * sizeof(u16);
    if (ws_size >= need) { CM = cands[i]; break; }
  }

  dim3 tb(32, 8);
  transpose_cvt<<<dim3(32, 8), tb, 0, stream>>>(w1, w1t, 256, 1024);
  transpose_cvt<<<dim3(32, 32), tb, 0, stream>>>(w2, w2t, 1024, 1024);
  transpose_cvt<<<dim3(8, 32), tb, 0, stream>>>(w3, w3t, 1024, 256);

  if (CM) {
    u16* bufB = bufA + CM * 1024;
    const int nchunk = (int)(M / CM);
    for (int ci = 0; ci < nchunk; ++ci) {
      const float* xc = x + (size_t)ci * CM * 256;
      float* oc = out + (size_t)ci * CM * 256;
      gemm8<256, 0, true><<<(int)(CM / 256) * 4, 512, 0, stream>>>(xc, w1t, bufA, 1024, 4);
      gemm8<1024, 0, false><<<(int)(CM / 256) * 4, 512, 0, stream>>>(bufA, w2t, bufB, 1024, 4);
      gemm8<1024, 1, false><<<(int)(CM / 256), 512, 0, stream>>>(bufB, w3t, oc, 256, 1);
    }
  } else {
    mlp3_fused<<<M / 64, 512, 0, stream>>>(x, w1t, w2t, w3t, out);
  }
}